// Round 14
// baseline (380.063 us; speedup 1.0000x reference)
//
#include <hip/hip_runtime.h>
#include <hip/hip_bf16.h>
#include <math.h>

// All external tensors are FLOAT32. Internal GEMM/attention compute is bf16
// MFMA with fp32 accumulate; residual path fp32.

// ---------- types & helpers ----------
typedef __attribute__((ext_vector_type(8)))  __bf16 bf16x8;
typedef __attribute__((ext_vector_type(4)))  float  f32x4;
typedef __attribute__((ext_vector_type(16))) float  f32x16;

// round-half-up bf16 (2 VALU ops; differs from RNE only on exact ties)
__device__ __forceinline__ ushort f2bf(float f) {
    return (ushort)((__builtin_bit_cast(uint, f) + 0x8000u) >> 16);
}
__device__ __forceinline__ bf16x8 ld8(const ushort* p) {
    return __builtin_bit_cast(bf16x8, *(const uint4*)p);
}
__device__ __forceinline__ f32x4 mfma_bf16(bf16x8 a, bf16x8 b, f32x4 c) {
    return __builtin_amdgcn_mfma_f32_16x16x32_bf16(a, b, c, 0, 0, 0);
}
__device__ __forceinline__ f32x16 mfma32(bf16x8 a, bf16x8 b, f32x16 c) {
    return __builtin_amdgcn_mfma_f32_32x32x16_bf16(a, b, c, 0, 0, 0);
}
__device__ __forceinline__ float fast_exp2(float x) {
#if __has_builtin(__builtin_amdgcn_exp2f)
    return __builtin_amdgcn_exp2f(x);
#else
    return exp2f(x);
#endif
}
__device__ __forceinline__ float fast_rcp(float x) {
#if __has_builtin(__builtin_amdgcn_rcpf)
    return __builtin_amdgcn_rcpf(x);
#else
    return 1.f / x;
#endif
}
// GELU with A&S 7.1.26 erf (|eps|<=1.5e-7 — invisible at bf16; ~12 VALU ops
// vs libm erff's ~25-30, which made step 6's VALUBusy 45%).
__device__ __forceinline__ float gelu_f(float v) {
    const float ax = fabsf(v) * 0.70710678118654752f;   // |v|/sqrt(2)
    const float t  = fast_rcp(fmaf(0.3275911f, ax, 1.f));
    const float p  = t * fmaf(t, fmaf(t, fmaf(t, fmaf(t, 1.061405429f,
                         -1.453152027f), 1.421413741f), -0.284496736f),
                         0.254829592f);
    const float e  = fast_exp2(-1.4426950408889634f * ax * ax);  // exp(-x^2)
    const float er = copysignf(fmaf(-p, e, 1.f), v);             // erf(v/sqrt2)
    return 0.5f * v * (1.f + er);
}
// scale 8 packed bf16 by fp32 constant, round back to bf16
__device__ __forceinline__ bf16x8 scale_bf8(bf16x8 v, float c) {
    uint4 u = __builtin_bit_cast(uint4, v);
    uint a[4] = {u.x, u.y, u.z, u.w};
#pragma unroll
    for (int i = 0; i < 4; i++) {
        float lo = __builtin_bit_cast(float, a[i] << 16);
        float hi = __builtin_bit_cast(float, a[i] & 0xffff0000u);
        lo *= c; hi *= c;
        a[i] = ((__builtin_bit_cast(uint, lo) + 0x8000u) >> 16)
             | ((__builtin_bit_cast(uint, hi) + 0x8000u) & 0xffff0000u);
    }
    uint4 r = {a[0], a[1], a[2], a[3]};
    return __builtin_bit_cast(bf16x8, r);
}
// async global->LDS, 16B per lane; LDS dest = wave-uniform base + lane*16
__device__ __forceinline__ void gl_lds16(const ushort* g, ushort* l) {
    __builtin_amdgcn_global_load_lds(
        (const __attribute__((address_space(1))) void*)g,
        (__attribute__((address_space(3))) void*)l, 16, 0, 0);
}
// pack two f32 -> one dword of 2x bf16 (RNE), hardware packed convert
__device__ __forceinline__ uint cvtpk(float lo, float hi) {
    uint r;
    asm("v_cvt_pk_bf16_f32 %0, %1, %2" : "=v"(r) : "v"(lo), "v"(hi));
    return r;
}
// swap hi 32 lanes of a with lo 32 lanes of b (both updated in place)
__device__ __forceinline__ void pl32swap(uint& a, uint& b) {
    asm("v_permlane32_swap_b32 %0, %1" : "+v"(a), "+v"(b));
}
// build PV A-fragment (16 keys) from 8 per-lane exp'd scores.
// p[r] = P[q=lane&31][key=(r&3)+8*(r>>2)+4*(lane>>5)] (32x32 C-layout).
// A-frag element j must be key 8*(lane>>5)+j: swap moves the cross-half words.
__device__ __forceinline__ bf16x8 packA(const float* p) {
    uint w0 = cvtpk(p[0], p[1]);   // keys (0,1)|(4,5)
    uint w2 = cvtpk(p[4], p[5]);   // keys (8,9)|(12,13)
    uint w1 = cvtpk(p[2], p[3]);   // keys (2,3)|(6,7)
    uint w3 = cvtpk(p[6], p[7]);   // keys (10,11)|(14,15)
    pl32swap(w0, w2);              // w0 -> j=0,1 ; w2 -> j=4,5 (both halves)
    pl32swap(w1, w3);              // w1 -> j=2,3 ; w3 -> j=6,7
    uint4 u = {w0, w1, w2, w3};
    return __builtin_bit_cast(bf16x8, u);
}

// ---------- fused 4-matrix transpose+convert: out_bf16[C][R] = in_f32[R][C] ----------
__global__ void transpose4_f2b(const float* __restrict__ s0, ushort* __restrict__ d0,
                               const float* __restrict__ s1, ushort* __restrict__ d1,
                               const float* __restrict__ s2, ushort* __restrict__ d2,
                               const float* __restrict__ s3, ushort* __restrict__ d3) {
    int id = blockIdx.x;
    const float* in; ushort* out; int R, C, tilesx;
    if (id < 1728)      { in = s0; out = d0; R = 768;  C = 2304; tilesx = 72; }
    else if ((id -= 1728) < 576)  { in = s1; out = d1; R = 768;  C = 768;  tilesx = 24; }
    else if ((id -= 576) < 2304)  { in = s2; out = d2; R = 768;  C = 3072; tilesx = 96; }
    else { id -= 2304;              in = s3; out = d3; R = 3072; C = 768;  tilesx = 24; }
    const int ty = id / tilesx, tx2 = id % tilesx;
    const int c0 = tx2 * 32, r0 = ty * 32;
    __shared__ float tile[32][33];
    const int tx = threadIdx.x & 31, tyy = threadIdx.x >> 5;
    for (int i = tyy; i < 32; i += 8)
        tile[i][tx] = in[(size_t)(r0 + i) * C + (c0 + tx)];
    __syncthreads();
    for (int i = tyy; i < 32; i += 8)
        out[(size_t)(c0 + i) * R + (r0 + tx)] = f2bf(tile[tx][i]);
}

// ---------- V transpose: vt[(bb*12+hh)*64 + d][n] = V[bb][n][hh][d] (bf16) ----------
__global__ void transpose_v(const ushort* __restrict__ qkv, ushort* __restrict__ vt) {
    const int bh = blockIdx.y;               // 48 = bb*12+hh
    const int til = blockIdx.x;              // 128 = 64 n-tiles x 2 d-tiles
    const int n0 = (til >> 1) * 32, d0 = (til & 1) * 32;
    __shared__ ushort tile[32][33];
    const int tx = threadIdx.x & 31, ty = threadIdx.x >> 5;
    const int bb = bh / 12, hh = bh - bb * 12;
    const ushort* src = qkv + (size_t)(bb * 2048) * 2304 + 1536 + hh * 64;
#pragma unroll
    for (int i = ty; i < 32; i += 8)
        tile[i][tx] = src[(size_t)(n0 + i) * 2304 + d0 + tx];
    __syncthreads();
    ushort* dst = vt + (size_t)bh * 64 * 2048;
#pragma unroll
    for (int i = ty; i < 32; i += 8)
        dst[(size_t)(d0 + i) * 2048 + n0 + tx] = tile[tx][i];
}

// ---------- layernorm: 768 cols, fp32 in -> bf16 out, one block per row ----------
__global__ void ln_kernel(const float* __restrict__ xin, const float* __restrict__ g,
                          const float* __restrict__ b, ushort* __restrict__ out) {
    const int row = blockIdx.x, t = threadIdx.x;
    float v[3]; float s = 0.f, s2 = 0.f;
#pragma unroll
    for (int i = 0; i < 3; i++) {
        const int c = t + i * 256;
        float f = xin[(size_t)row * 768 + c];
        v[i] = f; s += f; s2 += f * f;
    }
#pragma unroll
    for (int m = 1; m < 64; m <<= 1) { s += __shfl_xor(s, m); s2 += __shfl_xor(s2, m); }
    __shared__ float ss[8];
    const int w = t >> 6;
    if ((t & 63) == 0) { ss[w] = s; ss[w + 4] = s2; }
    __syncthreads();
    s  = ss[0] + ss[1] + ss[2] + ss[3];
    s2 = ss[4] + ss[5] + ss[6] + ss[7];
    const float mu = s * (1.f / 768.f);
    const float rs = rsqrtf(s2 * (1.f / 768.f) - mu * mu + 1e-5f);
#pragma unroll
    for (int i = 0; i < 3; i++) {
        const int c = t + i * 256;
        out[(size_t)row * 768 + c] = f2bf((v[i] - mu) * rs * g[c] + b[c]);
    }
}

// ---------- GEMM (unified): 128x64 tile, BK=64, 2-buf 1-barrier, XCD-grouped ----------
// Round-14: r12's attn addressing idiom applied here — the 12 swizzled LDS
// read pointers (8 A-frag + 4 B-frag) are loop-invariant modulo buffer
// parity, so precompute them ONCE and unroll the K-loop by 2 (nsteps = K/64
// is always even: 12 or 48). Every ds_read_b128 is then base-VGPR + literal
// immediate -> zero per-step address VALU (was: 12 XOR-addr recomputes/iter,
// VALUBusy 35% on the gelu GEMM). Stage order/barriers identical to r13.
// 16 MFMA per wave per barrier; 48KB LDS -> 3 blocks/CU; 8-chunk XOR swizzle
// (conflict-free); XCD M-grouped decode; ACT uses gelu_f (A&S erf).
template<int ACT, int RES, int OUTF32, int BIAS>
__launch_bounds__(256, 3)
__global__ void gemm_sk(const ushort* __restrict__ A, const ushort* __restrict__ BT,
                        const float* __restrict__ bias, const float* __restrict__ res,
                        void* __restrict__ out, int M, int N, int K) {
    __shared__ __align__(16) ushort As[2][128 * 64];
    __shared__ __align__(16) ushort Bs[2][64 * 64];
    // XCD M-grouped decode: same-XCD blocks share an A row-panel
    const int bid = blockIdx.x;
    const int xcd = bid & 7, j = bid >> 3;
    const int ntx = N / 64;
    const int mper = (M / 128) / 8;
    const int by = xcd * mper + j / ntx;
    const int bx = j - (j / ntx) * ntx;
    const int m0 = by * 128, n0 = bx * 64;
    const int t = threadIdx.x, lane = t & 63, w = t >> 6;
    const int wm = (w >> 1) * 64, wn = (w & 1) * 32;
    const int col = lane & 15, quad = lane >> 4;
    f32x4 acc[4][2] = {};
    // staging: lane covers LDS rows (base + lane>>3 + 8i), chunk lane&7;
    // content chunk = (lane&7) ^ ((lane>>3)&7)  (row bases are multiples of 8)
    const int srA = 32 * w + (lane >> 3);
    const int srB = 16 * w + (lane >> 3);
    const int sg  = (lane & 7) ^ ((lane >> 3) & 7);
    const ushort* Ag = A  + (size_t)(m0 + srA) * K + sg * 8;
    const ushort* Bg = BT + (size_t)(n0 + srB) * K + sg * 8;
    const size_t r8 = (size_t)8 * K;
    // precomputed LDS read pointers (loop-invariant; buf adds literal imm)
    const ushort* apA[4][2];
    const ushort* apB[2][2];
#pragma unroll
    for (int mi = 0; mi < 4; mi++)
#pragma unroll
        for (int kk = 0; kk < 2; kk++)
            apA[mi][kk] = &As[0][(wm + mi * 16 + col) * 64
                                 + (((kk * 4 + quad) ^ (col & 7)) << 3)];
#pragma unroll
    for (int ni = 0; ni < 2; ni++)
#pragma unroll
        for (int kk = 0; kk < 2; kk++)
            apB[ni][kk] = &Bs[0][(wn + ni * 16 + col) * 64
                                 + (((kk * 4 + quad) ^ (col & 7)) << 3)];
    auto STAGE = [&](int buf) {
        ushort* AsW = &As[buf][w * 2048];
        ushort* BsW = &Bs[buf][w * 1024];
#pragma unroll
        for (int i = 0; i < 4; i++) gl_lds16(Ag + i * r8, AsW + i * 512);
#pragma unroll
        for (int i = 0; i < 2; i++) gl_lds16(Bg + i * r8, BsW + i * 512);
        Ag += 64; Bg += 64;
    };
    auto COMPUTE = [&](int buf) {                // buf literal at all call sites
        const int ao = buf * (128 * 64);         // ushort offsets (literal)
        const int bo = buf * (64 * 64);
        bf16x8 af[4][2], bfr[2][2];
#pragma unroll
        for (int mi = 0; mi < 4; mi++)
#pragma unroll
            for (int kk = 0; kk < 2; kk++)
                af[mi][kk] = ld8(apA[mi][kk] + ao);
#pragma unroll
        for (int ni = 0; ni < 2; ni++)
#pragma unroll
            for (int kk = 0; kk < 2; kk++)
                bfr[ni][kk] = ld8(apB[ni][kk] + bo);
#pragma unroll
        for (int kk = 0; kk < 2; kk++)
#pragma unroll
            for (int mi = 0; mi < 4; mi++)
#pragma unroll
                for (int ni = 0; ni < 2; ni++)
                    acc[mi][ni] = mfma_bf16(af[mi][kk], bfr[ni][kk], acc[mi][ni]);
    };
    const int nsteps = K / 64;                   // 12 or 48 — always even
    STAGE(0);
    __syncthreads();                             // tile 0 ready
    for (int s = 0; s < nsteps; s += 2) {
        STAGE(1);                                // tile s+1 (overlaps compute)
        COMPUTE(0);
        __syncthreads();                         // tile s+1 ready; buf0 reads done
        if (s + 2 < nsteps) STAGE(0);            // tile s+2
        COMPUTE(1);
        __syncthreads();                         // tile s+2 ready; buf1 reads done
    }
#pragma unroll
    for (int mi = 0; mi < 4; mi++) {
#pragma unroll
        for (int ni = 0; ni < 2; ni++) {
            const int cc = n0 + wn + ni * 16 + col;
            float bv = 0.f;
            if (BIAS) bv = bias[cc];
#pragma unroll
            for (int r = 0; r < 4; r++) {
                const int rr = m0 + wm + mi * 16 + quad * 4 + r;
                const size_t idx = (size_t)rr * N + cc;
                float vv = acc[mi][ni][r] + bv;
                if (ACT == 1) vv = gelu_f(vv);
                if (RES == 1) vv += res[idx];
                if (OUTF32) ((float*)out)[idx] = vv;
                else        ((ushort*)out)[idx] = f2bf(vv);
            }
        }
    }
}

// ---------- flash attention: in-register softmax + LDS-staged K/V ----------
// r13 config (best verified): flat-KV compile-time addressing (4 lane-dep
// base pointers + kb-loop unrolled x2 -> every ds_read_b128 is base + literal
// imm), fp32 lsum row sums + shfl epilogue (absmax 0.03125).
// KV layout (ushort idx): K0[0..4095] K1[4096..] V0[8192..] V1[12288..16383].
// ap[c] = KV + lk*64 + (((2c+hi)^(lk&7))*8): K chunk set (kd*2+hi) and V chunk
// set (ks*4+kc*2+hi) are the same {hi,2+hi,4+hi,6+hi} -> shared bases.
#define EXPC 0.18033688f   /* (1/8) * log2(e): exp(s/8) = exp2(s_scaled) */
__launch_bounds__(256, 3)
__global__ void attn_kernel(const ushort* __restrict__ qkv,
                            const ushort* __restrict__ vt,
                            ushort* __restrict__ o) {
    // XCD-aware decode: blocks with same (bb,hh) land on same XCD (bid%8 heuristic)
    const int bid = blockIdx.x;                 // 0..767
    const int xcd = bid & 7, j = bid >> 3;      // j: 0..95
    const int qt = j & 15;
    const int c = xcd + 8 * (j >> 4);           // 0..47 head-combo
    const int bb = c / 12, hh = c - 12 * bb;
    const int t = threadIdx.x, lane = t & 63, w = t >> 6;
    const int lk = lane & 31, hi = lane >> 5;
    const int q0 = qt * 128 + w * 32;

    __shared__ __align__(16) ushort KV[16384];   // K dbuf | V dbuf, swizzled

    // Q B-frag: col q = lk, k(d) = 16*kd + 8*hi + j ; pre-scaled by EXPC
    bf16x8 qf[4];
    {
        const ushort* Qg = qkv + (size_t)(bb * 2048 + q0 + lk) * 2304 + hh * 64 + hi * 8;
#pragma unroll
        for (int kd = 0; kd < 4; kd++)
            qf[kd] = scale_bf8(__builtin_bit_cast(bf16x8, *(const uint4*)(Qg + kd * 16)),
                               EXPC);
    }

    // staging geometry: thread t covers LDS chunk (row = t>>3, c = t&7) and row+32.
    // content chunk g = c ^ (row&7)  (same for row+32: low 3 bits unchanged)
    const int srow = t >> 3, sg = (t & 7) ^ (srow & 7);
    const ushort* Kg = qkv + (size_t)(bb * 2048 + srow) * 2304 + 768 + hh * 64 + sg * 8;
    const ushort* Vg = vt + ((size_t)(bb * 12 + hh) * 64 + srow) * 2048 + sg * 8;

    // 4 lane-dependent LDS read bases (all reads = ap[c] + compile-time imm)
    const ushort* ap[4];
#pragma unroll
    for (int cc = 0; cc < 4; cc++)
        ap[cc] = KV + lk * 64 + (((cc * 2 + hi) ^ (lk & 7)) << 3);

    f32x16 oacc0 = {}, oacc1 = {};   // output d-halves (dt = 0 / 1)
    float lsum = 0.f;                // fp32 row-sum (r11 numerics)

    auto STAGE = [&](int buf, int kb) {          // buf literal at all call sites
        const ushort* kp = Kg + (size_t)(kb * 64) * 2304;
        const ushort* vp = Vg + kb * 64;
        ushort* kd = KV + buf * 4096;
        ushort* vd = KV + 8192 + buf * 4096;
        gl_lds16(kp,                       kd + w * 512);
        gl_lds16(kp + (size_t)32 * 2304,   kd + 2048 + w * 512);
        gl_lds16(vp,                       vd + w * 512);
        gl_lds16(vp + (size_t)32 * 2048,   vd + 2048 + w * 512);
    };
    auto STEP = [&](int buf, int ks) {           // buf, ks literals -> imm offsets
        const int kofs = buf * 4096 + ks * 2048;         // K tile (ushort idx)
        const int vofs = 8192 + buf * 4096;              // V tile base
        bf16x8 kf[4];
#pragma unroll
        for (int kd = 0; kd < 4; kd++)           // K[ks*32+lk][chunk kd*2+hi]
            kf[kd] = ld8(ap[kd] + kofs);
        f32x16 s = {};
#pragma unroll
        for (int kd = 0; kd < 4; kd++)
            s = mfma32(kf[kd], qf[kd], s);
        float p[16];
#pragma unroll
        for (int r = 0; r < 16; r++) { p[r] = fast_exp2(s[r]); lsum += p[r]; }
        bf16x8 pa0 = packA(p);                   // keys ks*32 + 0..15
        bf16x8 pa1 = packA(p + 8);               // keys ks*32 + 16..31
        bf16x8 v00 = ld8(ap[ks * 2]     + vofs);         // dt=0, keys ..+0..15
        bf16x8 v01 = ld8(ap[ks * 2]     + vofs + 2048);  // dt=1
        bf16x8 v10 = ld8(ap[ks * 2 + 1] + vofs);         // dt=0, keys ..+16..31
        bf16x8 v11 = ld8(ap[ks * 2 + 1] + vofs + 2048);  // dt=1
        oacc0 = mfma32(pa0, v00, oacc0);
        oacc1 = mfma32(pa0, v01, oacc1);
        oacc0 = mfma32(pa1, v10, oacc0);
        oacc1 = mfma32(pa1, v11, oacc1);
    };

    STAGE(0, 0);
    __syncthreads();                       // vmcnt drained: tile 0 ready
    for (int kb = 0; kb < 32; kb += 2) {   // unrolled x2: buf parity compile-time
        STAGE(1, kb + 1);                  // overlaps with compute below
        STEP(0, 0);
        STEP(0, 1);
        __syncthreads();                   // tile kb+1 ready; buf0 reads done
        if (kb + 2 < 32) STAGE(0, kb + 2);
        STEP(1, 0);
        STEP(1, 1);
        __syncthreads();                   // tile kb+2 ready; buf1 reads done
    }

    // full row sums: lane q and q+32 hold the two halves (r11 epilogue)
    lsum += __shfl_xor(lsum, 32);
    const size_t obase = (size_t)(bb * 2048 + q0) * 768 + hh * 64 + lk;
#pragma unroll
    for (int r = 0; r < 16; r++) {
        const int rowq = (r & 3) + 8 * (r >> 2) + 4 * hi;   // 32x32 C-layout row
        const float inv = 1.f / __shfl(lsum, rowq);
        o[obase + (size_t)rowq * 768]      = f2bf(oacc0[r] * inv);
        o[obase + (size_t)rowq * 768 + 32] = f2bf(oacc1[r] * inv);
    }
}

// ---------- launch ----------
// Workspace: tmpC 12.58 + big 50.33 + w1T 4.72 + w2T 4.72 = 72.4MB.
// wqkvT/wprojT live in big's tail; x1 (fp32) lives in d_out.
// vT (bf16 V-transpose, 12.58MB) also lives in d_out — dead until step 4 writes x1.
extern "C" void kernel_launch(void* const* d_in, const int* in_sizes, int n_in,
                              void* d_out, int out_size, void* d_ws, size_t ws_size,
                              hipStream_t stream) {
    const float* x     = (const float*)d_in[0];
    const float* ln1g  = (const float*)d_in[1];
    const float* ln1b  = (const float*)d_in[2];
    const float* wqkv  = (const float*)d_in[3];
    const float* wproj = (const float*)d_in[4];
    const float* bproj = (const float*)d_in[5];
    const float* ln2g  = (const float*)d_in[6];
    const float* ln2b  = (const float*)d_in[7];
    const float* w1    = (const float*)d_in[8];
    const float* b1    = (const float*)d_in[9];
    const float* w2    = (const float*)d_in[10];
    const float* b2    = (const float*)d_in[11];

    char* ws = (char*)d_ws;
    size_t off = 0;
    auto alloc = [&](size_t bytes) {
        char* p = ws + off; off += (bytes + 255) & ~(size_t)255; return p;
    };
    ushort* tmpC = (ushort*)alloc(8192ull * 768 * 2);    // h -> o -> h2 (bf16)
    ushort* big  = (ushort*)alloc(8192ull * 3072 * 2);   // qkv -> ff (bf16)
    ushort* w1T  = (ushort*)alloc(3072ull * 768 * 2);
    ushort* w2T  = (ushort*)alloc(768ull * 3072 * 2);
    ushort* wqkvT  = big + 8192ull * 2304;               // big tail (dead until FF)
    ushort* wprojT = wqkvT + 2304ull * 768;
    float*  x1     = (float*)d_out;                      // fp32 residual in d_out
    ushort* vT     = (ushort*)d_out;                     // V^T scratch (pre-step-4)

    transpose4_f2b<<<6912, 256, 0, stream>>>(wqkv, wqkvT, wproj, wprojT,
                                             w1, w1T, w2, w2T);

    // 1) h = LN1(x)
    ln_kernel<<<8192, 256, 0, stream>>>(x, ln1g, ln1b, tmpC);
    // 2) qkv = h @ w_qkv   (2304 blocks, XCD-grouped)
    gemm_sk<0, 0, 0, 0><<<2304, 256, 0, stream>>>(
        tmpC, wqkvT, nullptr, nullptr, big, 8192, 2304, 768);
    // 2b) V^T for attention B-frags
    transpose_v<<<dim3(128, 48), 256, 0, stream>>>(big, vT);
    // 3) o = attention(qkv)
    attn_kernel<<<768, 256, 0, stream>>>(big, vT, tmpC);
    // 4) x1 = x + o @ w_proj + b_proj  (768 blocks, XCD-grouped)
    gemm_sk<0, 1, 1, 1><<<768, 256, 0, stream>>>(
        tmpC, wprojT, bproj, x, x1, 8192, 768, 768);
    // 5) h2 = LN2(x1)
    ln_kernel<<<8192, 256, 0, stream>>>(x1, ln2g, ln2b, tmpC);
    // 6) ff = gelu(h2 @ w1 + b1)   (3072 blocks, XCD-grouped, fast-erf GELU)
    gemm_sk<1, 0, 0, 1><<<3072, 256, 0, stream>>>(
        tmpC, w1T, b1, nullptr, big, 8192, 3072, 768);
    // 7) out = x1 + ff @ w2 + b2   (768 blocks, XCD-grouped;
    //    res aliases out, read-before-write per element)
    gemm_sk<0, 1, 1, 1><<<768, 256, 0, stream>>>(
        big, w2T, b2, x1, d_out, 8192, 768, 3072);
}

// Round 15
// 358.256 us; speedup vs baseline: 1.0609x; 1.0609x over previous
//
#include <hip/hip_runtime.h>
#include <hip/hip_bf16.h>
#include <math.h>

// All external tensors are FLOAT32. Internal GEMM/attention compute is bf16
// MFMA with fp32 accumulate; residual path fp32.

// ---------- types & helpers ----------
typedef __attribute__((ext_vector_type(8)))  __bf16 bf16x8;
typedef __attribute__((ext_vector_type(4)))  float  f32x4;
typedef __attribute__((ext_vector_type(16))) float  f32x16;

// round-half-up bf16 (2 VALU ops; differs from RNE only on exact ties)
__device__ __forceinline__ ushort f2bf(float f) {
    return (ushort)((__builtin_bit_cast(uint, f) + 0x8000u) >> 16);
}
__device__ __forceinline__ bf16x8 ld8(const ushort* p) {
    return __builtin_bit_cast(bf16x8, *(const uint4*)p);
}
__device__ __forceinline__ f32x4 mfma_bf16(bf16x8 a, bf16x8 b, f32x4 c) {
    return __builtin_amdgcn_mfma_f32_16x16x32_bf16(a, b, c, 0, 0, 0);
}
__device__ __forceinline__ f32x16 mfma32(bf16x8 a, bf16x8 b, f32x16 c) {
    return __builtin_amdgcn_mfma_f32_32x32x16_bf16(a, b, c, 0, 0, 0);
}
__device__ __forceinline__ float fast_exp2(float x) {
#if __has_builtin(__builtin_amdgcn_exp2f)
    return __builtin_amdgcn_exp2f(x);
#else
    return exp2f(x);
#endif
}
__device__ __forceinline__ float fast_rcp(float x) {
#if __has_builtin(__builtin_amdgcn_rcpf)
    return __builtin_amdgcn_rcpf(x);
#else
    return 1.f / x;
#endif
}
// GELU with A&S 7.1.26 erf (|eps|<=1.5e-7 — invisible at bf16; ~12 VALU ops
// vs libm erff's ~25-30, which made step 6's VALUBusy 45%).
__device__ __forceinline__ float gelu_f(float v) {
    const float ax = fabsf(v) * 0.70710678118654752f;   // |v|/sqrt(2)
    const float t  = fast_rcp(fmaf(0.3275911f, ax, 1.f));
    const float p  = t * fmaf(t, fmaf(t, fmaf(t, fmaf(t, 1.061405429f,
                         -1.453152027f), 1.421413741f), -0.284496736f),
                         0.254829592f);
    const float e  = fast_exp2(-1.4426950408889634f * ax * ax);  // exp(-x^2)
    const float er = copysignf(fmaf(-p, e, 1.f), v);             // erf(v/sqrt2)
    return 0.5f * v * (1.f + er);
}
// scale 8 packed bf16 by fp32 constant, round back to bf16
__device__ __forceinline__ bf16x8 scale_bf8(bf16x8 v, float c) {
    uint4 u = __builtin_bit_cast(uint4, v);
    uint a[4] = {u.x, u.y, u.z, u.w};
#pragma unroll
    for (int i = 0; i < 4; i++) {
        float lo = __builtin_bit_cast(float, a[i] << 16);
        float hi = __builtin_bit_cast(float, a[i] & 0xffff0000u);
        lo *= c; hi *= c;
        a[i] = ((__builtin_bit_cast(uint, lo) + 0x8000u) >> 16)
             | ((__builtin_bit_cast(uint, hi) + 0x8000u) & 0xffff0000u);
    }
    uint4 r = {a[0], a[1], a[2], a[3]};
    return __builtin_bit_cast(bf16x8, r);
}
// async global->LDS, 16B per lane; LDS dest = wave-uniform base + lane*16
__device__ __forceinline__ void gl_lds16(const ushort* g, ushort* l) {
    __builtin_amdgcn_global_load_lds(
        (const __attribute__((address_space(1))) void*)g,
        (__attribute__((address_space(3))) void*)l, 16, 0, 0);
}
// pack two f32 -> one dword of 2x bf16 (RNE), hardware packed convert
__device__ __forceinline__ uint cvtpk(float lo, float hi) {
    uint r;
    asm("v_cvt_pk_bf16_f32 %0, %1, %2" : "=v"(r) : "v"(lo), "v"(hi));
    return r;
}
// swap hi 32 lanes of a with lo 32 lanes of b (both updated in place)
__device__ __forceinline__ void pl32swap(uint& a, uint& b) {
    asm("v_permlane32_swap_b32 %0, %1" : "+v"(a), "+v"(b));
}
// build PV A-fragment (16 keys) from 8 per-lane exp'd scores.
// p[r] = P[q=lane&31][key=(r&3)+8*(r>>2)+4*(lane>>5)] (32x32 C-layout).
// A-frag element j must be key 8*(lane>>5)+j: swap moves the cross-half words.
__device__ __forceinline__ bf16x8 packA(const float* p) {
    uint w0 = cvtpk(p[0], p[1]);   // keys (0,1)|(4,5)
    uint w2 = cvtpk(p[4], p[5]);   // keys (8,9)|(12,13)
    uint w1 = cvtpk(p[2], p[3]);   // keys (2,3)|(6,7)
    uint w3 = cvtpk(p[6], p[7]);   // keys (10,11)|(14,15)
    pl32swap(w0, w2);              // w0 -> j=0,1 ; w2 -> j=4,5 (both halves)
    pl32swap(w1, w3);              // w1 -> j=2,3 ; w3 -> j=6,7
    uint4 u = {w0, w1, w2, w3};
    return __builtin_bit_cast(bf16x8, u);
}

// ---------- fused 4-matrix transpose+convert: out_bf16[C][R] = in_f32[R][C] ----------
__global__ void transpose4_f2b(const float* __restrict__ s0, ushort* __restrict__ d0,
                               const float* __restrict__ s1, ushort* __restrict__ d1,
                               const float* __restrict__ s2, ushort* __restrict__ d2,
                               const float* __restrict__ s3, ushort* __restrict__ d3) {
    int id = blockIdx.x;
    const float* in; ushort* out; int R, C, tilesx;
    if (id < 1728)      { in = s0; out = d0; R = 768;  C = 2304; tilesx = 72; }
    else if ((id -= 1728) < 576)  { in = s1; out = d1; R = 768;  C = 768;  tilesx = 24; }
    else if ((id -= 576) < 2304)  { in = s2; out = d2; R = 768;  C = 3072; tilesx = 96; }
    else { id -= 2304;              in = s3; out = d3; R = 3072; C = 768;  tilesx = 24; }
    const int ty = id / tilesx, tx2 = id % tilesx;
    const int c0 = tx2 * 32, r0 = ty * 32;
    __shared__ float tile[32][33];
    const int tx = threadIdx.x & 31, tyy = threadIdx.x >> 5;
    for (int i = tyy; i < 32; i += 8)
        tile[i][tx] = in[(size_t)(r0 + i) * C + (c0 + tx)];
    __syncthreads();
    for (int i = tyy; i < 32; i += 8)
        out[(size_t)(c0 + i) * R + (r0 + tx)] = f2bf(tile[tx][i]);
}

// ---------- V transpose: vt[(bb*12+hh)*64 + d][n] = V[bb][n][hh][d] (bf16) ----------
__global__ void transpose_v(const ushort* __restrict__ qkv, ushort* __restrict__ vt) {
    const int bh = blockIdx.y;               // 48 = bb*12+hh
    const int til = blockIdx.x;              // 128 = 64 n-tiles x 2 d-tiles
    const int n0 = (til >> 1) * 32, d0 = (til & 1) * 32;
    __shared__ ushort tile[32][33];
    const int tx = threadIdx.x & 31, ty = threadIdx.x >> 5;
    const int bb = bh / 12, hh = bh - bb * 12;
    const ushort* src = qkv + (size_t)(bb * 2048) * 2304 + 1536 + hh * 64;
#pragma unroll
    for (int i = ty; i < 32; i += 8)
        tile[i][tx] = src[(size_t)(n0 + i) * 2304 + d0 + tx];
    __syncthreads();
    ushort* dst = vt + (size_t)bh * 64 * 2048;
#pragma unroll
    for (int i = ty; i < 32; i += 8)
        dst[(size_t)(d0 + i) * 2048 + n0 + tx] = tile[tx][i];
}

// ---------- layernorm: 768 cols, fp32 in -> bf16 out, one block per row ----------
__global__ void ln_kernel(const float* __restrict__ xin, const float* __restrict__ g,
                          const float* __restrict__ b, ushort* __restrict__ out) {
    const int row = blockIdx.x, t = threadIdx.x;
    float v[3]; float s = 0.f, s2 = 0.f;
#pragma unroll
    for (int i = 0; i < 3; i++) {
        const int c = t + i * 256;
        float f = xin[(size_t)row * 768 + c];
        v[i] = f; s += f; s2 += f * f;
    }
#pragma unroll
    for (int m = 1; m < 64; m <<= 1) { s += __shfl_xor(s, m); s2 += __shfl_xor(s2, m); }
    __shared__ float ss[8];
    const int w = t >> 6;
    if ((t & 63) == 0) { ss[w] = s; ss[w + 4] = s2; }
    __syncthreads();
    s  = ss[0] + ss[1] + ss[2] + ss[3];
    s2 = ss[4] + ss[5] + ss[6] + ss[7];
    const float mu = s * (1.f / 768.f);
    const float rs = rsqrtf(s2 * (1.f / 768.f) - mu * mu + 1e-5f);
#pragma unroll
    for (int i = 0; i < 3; i++) {
        const int c = t + i * 256;
        out[(size_t)row * 768 + c] = f2bf((v[i] - mu) * rs * g[c] + b[c]);
    }
}

// ---------- GEMM (unified): 128x64 tile, BK=64, 2-buf 1-barrier, XCD-grouped ----------
// Round-15: PRECOMP template param resolves the r13/r14 A/B per instantiation.
// PRECOMP=1 (r14 path): precomputed LDS read pointers + K-loop unrolled x2 ->
//   ds_read = base + literal imm. Proven -4.5us on the ACT=1 gelu GEMM (r14).
// PRECOMP=0 (r13 path): rolled loop, inline swizzled addressing. The ACT=0
//   GEMMs (steps 2/4/7) were faster under it in r13 vs r14 (~22us combined).
// Common: 16 MFMA/wave/barrier; 48KB LDS -> 3 blocks/CU; 8-chunk XOR swizzle
// (conflict-free); XCD M-grouped decode; gelu_f (A&S erf).
template<int ACT, int RES, int OUTF32, int BIAS, int PRECOMP>
__launch_bounds__(256, 3)
__global__ void gemm_sk(const ushort* __restrict__ A, const ushort* __restrict__ BT,
                        const float* __restrict__ bias, const float* __restrict__ res,
                        void* __restrict__ out, int M, int N, int K) {
    __shared__ __align__(16) ushort As[2][128 * 64];
    __shared__ __align__(16) ushort Bs[2][64 * 64];
    // XCD M-grouped decode: same-XCD blocks share an A row-panel
    const int bid = blockIdx.x;
    const int xcd = bid & 7, j = bid >> 3;
    const int ntx = N / 64;
    const int mper = (M / 128) / 8;
    const int by = xcd * mper + j / ntx;
    const int bx = j - (j / ntx) * ntx;
    const int m0 = by * 128, n0 = bx * 64;
    const int t = threadIdx.x, lane = t & 63, w = t >> 6;
    const int wm = (w >> 1) * 64, wn = (w & 1) * 32;
    const int col = lane & 15, quad = lane >> 4;
    f32x4 acc[4][2] = {};
    // staging: lane covers LDS rows (base + lane>>3 + 8i), chunk lane&7;
    // content chunk = (lane&7) ^ ((lane>>3)&7)  (row bases are multiples of 8)
    const int srA = 32 * w + (lane >> 3);
    const int srB = 16 * w + (lane >> 3);
    const int sg  = (lane & 7) ^ ((lane >> 3) & 7);
    const ushort* Ag = A  + (size_t)(m0 + srA) * K + sg * 8;
    const ushort* Bg = BT + (size_t)(n0 + srB) * K + sg * 8;
    const size_t r8 = (size_t)8 * K;
    auto STAGE = [&](int buf) {
        ushort* AsW = &As[buf][w * 2048];
        ushort* BsW = &Bs[buf][w * 1024];
#pragma unroll
        for (int i = 0; i < 4; i++) gl_lds16(Ag + i * r8, AsW + i * 512);
#pragma unroll
        for (int i = 0; i < 2; i++) gl_lds16(Bg + i * r8, BsW + i * 512);
        Ag += 64; Bg += 64;
    };
    const int nsteps = K / 64;                   // 12 or 48 — always even
    if constexpr (PRECOMP == 1) {
        // r14 path: precomputed pointers, unrolled x2
        const ushort* apA[4][2];
        const ushort* apB[2][2];
#pragma unroll
        for (int mi = 0; mi < 4; mi++)
#pragma unroll
            for (int kk = 0; kk < 2; kk++)
                apA[mi][kk] = &As[0][(wm + mi * 16 + col) * 64
                                     + (((kk * 4 + quad) ^ (col & 7)) << 3)];
#pragma unroll
        for (int ni = 0; ni < 2; ni++)
#pragma unroll
            for (int kk = 0; kk < 2; kk++)
                apB[ni][kk] = &Bs[0][(wn + ni * 16 + col) * 64
                                     + (((kk * 4 + quad) ^ (col & 7)) << 3)];
        auto COMPUTE = [&](int buf) {            // buf literal at all call sites
            const int ao = buf * (128 * 64);
            const int bo = buf * (64 * 64);
            bf16x8 af[4][2], bfr[2][2];
#pragma unroll
            for (int mi = 0; mi < 4; mi++)
#pragma unroll
                for (int kk = 0; kk < 2; kk++)
                    af[mi][kk] = ld8(apA[mi][kk] + ao);
#pragma unroll
            for (int ni = 0; ni < 2; ni++)
#pragma unroll
                for (int kk = 0; kk < 2; kk++)
                    bfr[ni][kk] = ld8(apB[ni][kk] + bo);
#pragma unroll
            for (int kk = 0; kk < 2; kk++)
#pragma unroll
                for (int mi = 0; mi < 4; mi++)
#pragma unroll
                    for (int ni = 0; ni < 2; ni++)
                        acc[mi][ni] = mfma_bf16(af[mi][kk], bfr[ni][kk], acc[mi][ni]);
        };
        STAGE(0);
        __syncthreads();                         // tile 0 ready
        for (int s = 0; s < nsteps; s += 2) {
            STAGE(1);                            // tile s+1 (overlaps compute)
            COMPUTE(0);
            __syncthreads();                     // tile s+1 ready; buf0 reads done
            if (s + 2 < nsteps) STAGE(0);        // tile s+2
            COMPUTE(1);
            __syncthreads();                     // tile s+2 ready; buf1 reads done
        }
    } else {
        // r13 path: rolled loop, inline swizzled addressing
        STAGE(0);
        __syncthreads();                         // tile 0 ready
        for (int s = 0; s < nsteps; ++s) {
            const int cur = s & 1;
            if (s + 1 < nsteps) STAGE(cur ^ 1);  // overlaps with compute below
            bf16x8 af[4][2], bfr[2][2];
#pragma unroll
            for (int mi = 0; mi < 4; mi++)
#pragma unroll
                for (int kk = 0; kk < 2; kk++)
                    af[mi][kk] = ld8(&As[cur][(wm + mi * 16 + col) * 64
                                              + (((kk * 4 + quad) ^ (col & 7)) << 3)]);
#pragma unroll
            for (int ni = 0; ni < 2; ni++)
#pragma unroll
                for (int kk = 0; kk < 2; kk++)
                    bfr[ni][kk] = ld8(&Bs[cur][(wn + ni * 16 + col) * 64
                                               + (((kk * 4 + quad) ^ (col & 7)) << 3)]);
#pragma unroll
            for (int kk = 0; kk < 2; kk++)
#pragma unroll
                for (int mi = 0; mi < 4; mi++)
#pragma unroll
                    for (int ni = 0; ni < 2; ni++)
                        acc[mi][ni] = mfma_bf16(af[mi][kk], bfr[ni][kk], acc[mi][ni]);
            __syncthreads();                     // next tile ready; cur reads done
        }
    }
#pragma unroll
    for (int mi = 0; mi < 4; mi++) {
#pragma unroll
        for (int ni = 0; ni < 2; ni++) {
            const int cc = n0 + wn + ni * 16 + col;
            float bv = 0.f;
            if (BIAS) bv = bias[cc];
#pragma unroll
            for (int r = 0; r < 4; r++) {
                const int rr = m0 + wm + mi * 16 + quad * 4 + r;
                const size_t idx = (size_t)rr * N + cc;
                float vv = acc[mi][ni][r] + bv;
                if (ACT == 1) vv = gelu_f(vv);
                if (RES == 1) vv += res[idx];
                if (OUTF32) ((float*)out)[idx] = vv;
                else        ((ushort*)out)[idx] = f2bf(vv);
            }
        }
    }
}

// ---------- flash attention: in-register softmax + LDS-staged K/V ----------
// r13 config (best verified): flat-KV compile-time addressing (4 lane-dep
// base pointers + kb-loop unrolled x2 -> every ds_read_b128 is base + literal
// imm), fp32 lsum row sums + shfl epilogue (absmax 0.03125).
// KV layout (ushort idx): K0[0..4095] K1[4096..] V0[8192..] V1[12288..16383].
// ap[c] = KV + lk*64 + (((2c+hi)^(lk&7))*8): K chunk set (kd*2+hi) and V chunk
// set (ks*4+kc*2+hi) are the same {hi,2+hi,4+hi,6+hi} -> shared bases.
#define EXPC 0.18033688f   /* (1/8) * log2(e): exp(s/8) = exp2(s_scaled) */
__launch_bounds__(256, 3)
__global__ void attn_kernel(const ushort* __restrict__ qkv,
                            const ushort* __restrict__ vt,
                            ushort* __restrict__ o) {
    // XCD-aware decode: blocks with same (bb,hh) land on same XCD (bid%8 heuristic)
    const int bid = blockIdx.x;                 // 0..767
    const int xcd = bid & 7, j = bid >> 3;      // j: 0..95
    const int qt = j & 15;
    const int c = xcd + 8 * (j >> 4);           // 0..47 head-combo
    const int bb = c / 12, hh = c - 12 * bb;
    const int t = threadIdx.x, lane = t & 63, w = t >> 6;
    const int lk = lane & 31, hi = lane >> 5;
    const int q0 = qt * 128 + w * 32;

    __shared__ __align__(16) ushort KV[16384];   // K dbuf | V dbuf, swizzled

    // Q B-frag: col q = lk, k(d) = 16*kd + 8*hi + j ; pre-scaled by EXPC
    bf16x8 qf[4];
    {
        const ushort* Qg = qkv + (size_t)(bb * 2048 + q0 + lk) * 2304 + hh * 64 + hi * 8;
#pragma unroll
        for (int kd = 0; kd < 4; kd++)
            qf[kd] = scale_bf8(__builtin_bit_cast(bf16x8, *(const uint4*)(Qg + kd * 16)),
                               EXPC);
    }

    // staging geometry: thread t covers LDS chunk (row = t>>3, c = t&7) and row+32.
    // content chunk g = c ^ (row&7)  (same for row+32: low 3 bits unchanged)
    const int srow = t >> 3, sg = (t & 7) ^ (srow & 7);
    const ushort* Kg = qkv + (size_t)(bb * 2048 + srow) * 2304 + 768 + hh * 64 + sg * 8;
    const ushort* Vg = vt + ((size_t)(bb * 12 + hh) * 64 + srow) * 2048 + sg * 8;

    // 4 lane-dependent LDS read bases (all reads = ap[c] + compile-time imm)
    const ushort* ap[4];
#pragma unroll
    for (int cc = 0; cc < 4; cc++)
        ap[cc] = KV + lk * 64 + (((cc * 2 + hi) ^ (lk & 7)) << 3);

    f32x16 oacc0 = {}, oacc1 = {};   // output d-halves (dt = 0 / 1)
    float lsum = 0.f;                // fp32 row-sum (r11 numerics)

    auto STAGE = [&](int buf, int kb) {          // buf literal at all call sites
        const ushort* kp = Kg + (size_t)(kb * 64) * 2304;
        const ushort* vp = Vg + kb * 64;
        ushort* kd = KV + buf * 4096;
        ushort* vd = KV + 8192 + buf * 4096;
        gl_lds16(kp,                       kd + w * 512);
        gl_lds16(kp + (size_t)32 * 2304,   kd + 2048 + w * 512);
        gl_lds16(vp,                       vd + w * 512);
        gl_lds16(vp + (size_t)32 * 2048,   vd + 2048 + w * 512);
    };
    auto STEP = [&](int buf, int ks) {           // buf, ks literals -> imm offsets
        const int kofs = buf * 4096 + ks * 2048;         // K tile (ushort idx)
        const int vofs = 8192 + buf * 4096;              // V tile base
        bf16x8 kf[4];
#pragma unroll
        for (int kd = 0; kd < 4; kd++)           // K[ks*32+lk][chunk kd*2+hi]
            kf[kd] = ld8(ap[kd] + kofs);
        f32x16 s = {};
#pragma unroll
        for (int kd = 0; kd < 4; kd++)
            s = mfma32(kf[kd], qf[kd], s);
        float p[16];
#pragma unroll
        for (int r = 0; r < 16; r++) { p[r] = fast_exp2(s[r]); lsum += p[r]; }
        bf16x8 pa0 = packA(p);                   // keys ks*32 + 0..15
        bf16x8 pa1 = packA(p + 8);               // keys ks*32 + 16..31
        bf16x8 v00 = ld8(ap[ks * 2]     + vofs);         // dt=0, keys ..+0..15
        bf16x8 v01 = ld8(ap[ks * 2]     + vofs + 2048);  // dt=1
        bf16x8 v10 = ld8(ap[ks * 2 + 1] + vofs);         // dt=0, keys ..+16..31
        bf16x8 v11 = ld8(ap[ks * 2 + 1] + vofs + 2048);  // dt=1
        oacc0 = mfma32(pa0, v00, oacc0);
        oacc1 = mfma32(pa0, v01, oacc1);
        oacc0 = mfma32(pa1, v10, oacc0);
        oacc1 = mfma32(pa1, v11, oacc1);
    };

    STAGE(0, 0);
    __syncthreads();                       // vmcnt drained: tile 0 ready
    for (int kb = 0; kb < 32; kb += 2) {   // unrolled x2: buf parity compile-time
        STAGE(1, kb + 1);                  // overlaps with compute below
        STEP(0, 0);
        STEP(0, 1);
        __syncthreads();                   // tile kb+1 ready; buf0 reads done
        if (kb + 2 < 32) STAGE(0, kb + 2);
        STEP(1, 0);
        STEP(1, 1);
        __syncthreads();                   // tile kb+2 ready; buf1 reads done
    }

    // full row sums: lane q and q+32 hold the two halves (r11 epilogue)
    lsum += __shfl_xor(lsum, 32);
    const size_t obase = (size_t)(bb * 2048 + q0) * 768 + hh * 64 + lk;
#pragma unroll
    for (int r = 0; r < 16; r++) {
        const int rowq = (r & 3) + 8 * (r >> 2) + 4 * hi;   // 32x32 C-layout row
        const float inv = 1.f / __shfl(lsum, rowq);
        o[obase + (size_t)rowq * 768]      = f2bf(oacc0[r] * inv);
        o[obase + (size_t)rowq * 768 + 32] = f2bf(oacc1[r] * inv);
    }
}

// ---------- launch ----------
// Workspace: tmpC 12.58 + big 50.33 + w1T 4.72 + w2T 4.72 = 72.4MB.
// wqkvT/wprojT live in big's tail; x1 (fp32) lives in d_out.
// vT (bf16 V-transpose, 12.58MB) also lives in d_out — dead until step 4 writes x1.
extern "C" void kernel_launch(void* const* d_in, const int* in_sizes, int n_in,
                              void* d_out, int out_size, void* d_ws, size_t ws_size,
                              hipStream_t stream) {
    const float* x     = (const float*)d_in[0];
    const float* ln1g  = (const float*)d_in[1];
    const float* ln1b  = (const float*)d_in[2];
    const float* wqkv  = (const float*)d_in[3];
    const float* wproj = (const float*)d_in[4];
    const float* bproj = (const float*)d_in[5];
    const float* ln2g  = (const float*)d_in[6];
    const float* ln2b  = (const float*)d_in[7];
    const float* w1    = (const float*)d_in[8];
    const float* b1    = (const float*)d_in[9];
    const float* w2    = (const float*)d_in[10];
    const float* b2    = (const float*)d_in[11];

    char* ws = (char*)d_ws;
    size_t off = 0;
    auto alloc = [&](size_t bytes) {
        char* p = ws + off; off += (bytes + 255) & ~(size_t)255; return p;
    };
    ushort* tmpC = (ushort*)alloc(8192ull * 768 * 2);    // h -> o -> h2 (bf16)
    ushort* big  = (ushort*)alloc(8192ull * 3072 * 2);   // qkv -> ff (bf16)
    ushort* w1T  = (ushort*)alloc(3072ull * 768 * 2);
    ushort* w2T  = (ushort*)alloc(768ull * 3072 * 2);
    ushort* wqkvT  = big + 8192ull * 2304;               // big tail (dead until FF)
    ushort* wprojT = wqkvT + 2304ull * 768;
    float*  x1     = (float*)d_out;                      // fp32 residual in d_out
    ushort* vT     = (ushort*)d_out;                     // V^T scratch (pre-step-4)

    transpose4_f2b<<<6912, 256, 0, stream>>>(wqkv, wqkvT, wproj, wprojT,
                                             w1, w1T, w2, w2T);

    // 1) h = LN1(x)
    ln_kernel<<<8192, 256, 0, stream>>>(x, ln1g, ln1b, tmpC);
    // 2) qkv = h @ w_qkv   (2304 blocks, XCD-grouped, r13 rolled loop)
    gemm_sk<0, 0, 0, 0, 0><<<2304, 256, 0, stream>>>(
        tmpC, wqkvT, nullptr, nullptr, big, 8192, 2304, 768);
    // 2b) V^T for attention B-frags
    transpose_v<<<dim3(128, 48), 256, 0, stream>>>(big, vT);
    // 3) o = attention(qkv)
    attn_kernel<<<768, 256, 0, stream>>>(big, vT, tmpC);
    // 4) x1 = x + o @ w_proj + b_proj  (768 blocks, XCD-grouped, r13 rolled loop)
    gemm_sk<0, 1, 1, 1, 0><<<768, 256, 0, stream>>>(
        tmpC, wprojT, bproj, x, x1, 8192, 768, 768);
    // 5) h2 = LN2(x1)
    ln_kernel<<<8192, 256, 0, stream>>>(x1, ln2g, ln2b, tmpC);
    // 6) ff = gelu(h2 @ w1 + b1)   (3072 blocks, XCD-grouped, fast-erf GELU,
    //    r14 precomputed-pointer loop — proven -4.5us on this instantiation)
    gemm_sk<1, 0, 0, 1, 1><<<3072, 256, 0, stream>>>(
        tmpC, w1T, b1, nullptr, big, 8192, 3072, 768);
    // 7) out = x1 + ff @ w2 + b2   (768 blocks, XCD-grouped, r13 rolled loop;
    //    res aliases out, read-before-write per element)
    gemm_sk<0, 1, 1, 1, 0><<<768, 256, 0, stream>>>(
        big, w2T, b2, x1, d_out, 8192, 768, 3072);
}